// Round 1
// baseline (663.104 us; speedup 1.0000x reference)
//
#include <hip/hip_runtime.h>
#include <cfloat>
#include <cstdint>

// Problem constants (B=4, N=2048, C=64, O=64, K=20)
#define M_TOTAL 8192
#define KNN 20
#define NPART 16
#define CAND_PER_PART (M_TOTAL / NPART)  // 512

// ---------------------------------------------------------------------------
// K0: per-point precompute.
//   sq[j]  = ||pos_j||^2
//   a[j,o] = b1[o] + sum_d f[j,d] * (W1[d,o] - W1[64+d,o])   (center term + b1)
//   g[j,o] =         sum_d f[j,d] * W1[64+d,o]               (neighbor term)
// Then layer-1 hidden for edge (q,n) is relu(a_q + g_n): layer-1 GEMM cost
// collapses from per-edge to per-point.
// ---------------------------------------------------------------------------
__global__ __launch_bounds__(256) void k0_pre(
    const float* __restrict__ pos, const float* __restrict__ feat,
    const float* __restrict__ W1, const float* __restrict__ b1,
    float* __restrict__ sq, float* __restrict__ a_out, float* __restrict__ g_out) {
  __shared__ float fLds[4][64];
  const int lane = threadIdx.x & 63;
  const int rl = threadIdx.x >> 6;
  const int r = blockIdx.x * 4 + rl;

  float p = pos[r * 64 + lane];
  float f = feat[r * 64 + lane];
  fLds[rl][lane] = f;  // wave-private row; wave is lockstep, no __syncthreads

  // wave butterfly reduce for sq
  float s = p * p;
#pragma unroll
  for (int off = 1; off < 64; off <<= 1) s += __shfl_xor(s, off, 64);
  if (lane == 0) sq[r] = s;

  float acc_a = b1[lane];
  float acc_g = 0.f;
  const float4* f4 = reinterpret_cast<const float4*>(fLds[rl]);
#pragma unroll
  for (int i = 0; i < 16; ++i) {
    float4 fv = f4[i];
    float fd[4] = {fv.x, fv.y, fv.z, fv.w};
#pragma unroll
    for (int j = 0; j < 4; ++j) {
      int d = 4 * i + j;
      float wt = W1[d * 64 + lane];         // coalesced across lanes
      float wb = W1[(64 + d) * 64 + lane];  // coalesced across lanes
      acc_a = fmaf(fd[j], wt - wb, acc_a);
      acc_g = fmaf(fd[j], wb, acc_g);
    }
  }
  a_out[r * 64 + lane] = acc_a;
  g_out[r * 64 + lane] = acc_g;
}

// ---------------------------------------------------------------------------
// K1: partial KNN. Grid (32 query-blocks, 16 partitions). One thread = one
// query; scans 512 candidates of its partition. Candidate rows are
// block-uniform -> scalar-cache loads; query row lives in 64 VGPRs.
// Keeps sorted (ascending) top-20 (dist, idx) in registers via gated
// carry-swap insertion (strict < keeps earlier/smaller index on ties,
// matching jax.lax.top_k stability). Emits packed u64 keys sorted ascending.
// ---------------------------------------------------------------------------
__global__ __launch_bounds__(256) void k1_knn(
    const float* __restrict__ pos, const float* __restrict__ sq,
    unsigned long long* __restrict__ keys) {
  const int q = blockIdx.x * 256 + threadIdx.x;
  const int part = blockIdx.y;
  const int base = part * CAND_PER_PART;

  float qp[64];
  {
    const float4* qp4 = reinterpret_cast<const float4*>(pos + (size_t)q * 64);
#pragma unroll
    for (int i = 0; i < 16; ++i) {
      float4 v = qp4[i];
      qp[4 * i + 0] = v.x; qp[4 * i + 1] = v.y;
      qp[4 * i + 2] = v.z; qp[4 * i + 3] = v.w;
    }
  }
  const float qsq = sq[q];

  float bd[KNN];
  int bi[KNN];
#pragma unroll
  for (int k = 0; k < KNN; ++k) { bd[k] = FLT_MAX; bi[k] = 0x7fffffff; }

  for (int c = 0; c < CAND_PER_PART; ++c) {
    const int j = base + c;  // block-uniform
    const float4* cp4 = reinterpret_cast<const float4*>(pos + (size_t)j * 64);
    float d0 = 0.f, d1 = 0.f, d2 = 0.f, d3 = 0.f;
#pragma unroll
    for (int i = 0; i < 16; ++i) {
      float4 cv = cp4[i];  // uniform address -> scalar loads
      d0 = fmaf(cv.x, qp[4 * i + 0], d0);
      d1 = fmaf(cv.y, qp[4 * i + 1], d1);
      d2 = fmaf(cv.z, qp[4 * i + 2], d2);
      d3 = fmaf(cv.w, qp[4 * i + 3], d3);
    }
    float dot = (d0 + d1) + (d2 + d3);
    // same formula as reference: sq_i + sq_j - 2*dot; clamp >=0 so the
    // float-bit packing in K2 stays monotonic (self-distance can round <0)
    float dist = fmaxf(fmaf(-2.f, dot, qsq + sq[j]), 0.f);
    if (dist < bd[KNN - 1]) {
      float cd = dist;
      int ci = j;
#pragma unroll
      for (int k = 0; k < KNN; ++k) {
        bool sw = cd < bd[k];
        float nd = sw ? bd[k] : cd;
        int ni = sw ? bi[k] : ci;
        bd[k] = sw ? cd : bd[k];
        bi[k] = sw ? ci : bi[k];
        cd = nd; ci = ni;
      }
    }
  }

  unsigned long long* outp = keys + ((size_t)q * NPART + part) * KNN;
#pragma unroll
  for (int k = 0; k < KNN; ++k) {
    unsigned int db = __float_as_uint(bd[k]);
    outp[k] = ((unsigned long long)db << 32) | (unsigned int)bi[k];
  }
}

// ---------------------------------------------------------------------------
// K2: merge 16 sorted partial lists -> global top-20, then
// out[q,o] = b2[o] + max_k sum_d relu(a_q + g_{n_k})[d] * W2[d,o]
// One wave per query, 4 queries per block. W2 column in 64 VGPRs per lane.
// ---------------------------------------------------------------------------
__global__ __launch_bounds__(256) void k2_mlp(
    const float* __restrict__ a_in, const float* __restrict__ g_in,
    const float* __restrict__ W2, const float* __restrict__ b2,
    const unsigned long long* __restrict__ keys, float* __restrict__ out) {
  __shared__ unsigned long long kLds[4][NPART * KNN];  // 4*320*8 = 10 KiB
  __shared__ float hLds[4][64];                        // 1 KiB
  const int lane = threadIdx.x & 63;
  const int wv = threadIdx.x >> 6;
  const int q = blockIdx.x * 4 + wv;

  // stage this query's 320 keys, coalesced (wave-private region)
  const unsigned long long* kq = keys + (size_t)q * (NPART * KNN);
#pragma unroll
  for (int i = 0; i < 5; ++i) kLds[wv][lane + 64 * i] = kq[lane + 64 * i];
  __builtin_amdgcn_wave_barrier();

  // 16-way merge: lane p < 16 walks sorted list p; 20 rounds of wave-min.
  unsigned long long key = ~0ull, nxt = ~0ull;
  int ptr = 0;
  if (lane < NPART) {
    key = kLds[wv][lane * KNN + 0];
    nxt = kLds[wv][lane * KNN + 1];
  }
  int sel[KNN];
#pragma unroll
  for (int r = 0; r < KNN; ++r) {
    unsigned long long m = key;
#pragma unroll
    for (int s = 1; s < 64; s <<= 1) {
      unsigned long long o = __shfl_xor(m, s, 64);
      m = (o < m) ? o : m;
    }
    sel[r] = (int)(unsigned int)(m & 0xffffffffu);  // all lanes agree
    if (key == m) {  // unique winner (keys embed unique idx)
      ptr++;
      key = nxt;
      nxt = (ptr + 1 < KNN) ? kLds[wv][lane * KNN + ptr + 1] : ~0ull;
    }
  }

  // W2 column for this lane into registers (16 KiB matrix, L2-hot)
  float w2[64];
#pragma unroll
  for (int d = 0; d < 64; ++d) w2[d] = W2[d * 64 + lane];
  const float aq = a_in[(size_t)q * 64 + lane];

  float omax = -FLT_MAX;
#pragma unroll
  for (int k = 0; k < KNN; ++k) {
    const int n = sel[k];  // wave-uniform
    float hv = fmaxf(aq + g_in[(size_t)n * 64 + lane], 0.f);
    hLds[wv][lane] = hv;
    __builtin_amdgcn_wave_barrier();  // wave-lockstep LDS transpose
    float s0 = 0.f, s1 = 0.f, s2 = 0.f, s3 = 0.f;
    const float4* h4 = reinterpret_cast<const float4*>(hLds[wv]);
#pragma unroll
    for (int i = 0; i < 16; ++i) {
      float4 hv4 = h4[i];  // broadcast read
      s0 = fmaf(hv4.x, w2[4 * i + 0], s0);
      s1 = fmaf(hv4.y, w2[4 * i + 1], s1);
      s2 = fmaf(hv4.z, w2[4 * i + 2], s2);
      s3 = fmaf(hv4.w, w2[4 * i + 3], s3);
    }
    omax = fmaxf(omax, (s0 + s1) + (s2 + s3));
    __builtin_amdgcn_wave_barrier();
  }
  out[(size_t)q * 64 + lane] = omax + b2[lane];
}

// ---------------------------------------------------------------------------
extern "C" void kernel_launch(void* const* d_in, const int* in_sizes, int n_in,
                              void* d_out, int out_size, void* d_ws, size_t ws_size,
                              hipStream_t stream) {
  const float* pos = (const float*)d_in[0];
  const float* feat = (const float*)d_in[1];
  const float* W1 = (const float*)d_in[2];
  const float* b1 = (const float*)d_in[3];
  const float* W2 = (const float*)d_in[4];
  const float* b2 = (const float*)d_in[5];
  float* out = (float*)d_out;

  // ws layout: sq (32 KiB) | a (2 MiB) | g (2 MiB) | keys (20.97 MiB) ~= 25 MiB
  char* ws = (char*)d_ws;
  float* sq = (float*)ws;
  float* a = (float*)(ws + 32768);
  float* g = (float*)(ws + 32768 + 2097152);
  unsigned long long* keys = (unsigned long long*)(ws + 32768 + 2 * 2097152);

  k0_pre<<<M_TOTAL / 4, 256, 0, stream>>>(pos, feat, W1, b1, sq, a, g);
  k1_knn<<<dim3(M_TOTAL / 256, NPART), 256, 0, stream>>>(pos, sq, keys);
  k2_mlp<<<M_TOTAL / 4, 256, 0, stream>>>(a, g, W2, b2, keys, out);
}

// Round 4
// 374.179 us; speedup vs baseline: 1.7722x; 1.7722x over previous
//
#include <hip/hip_runtime.h>
#include <cfloat>
#include <cstdint>

// Problem constants (B=4, N=2048, C=64, O=64, K=20)
#define M_TOTAL 8192
#define KNN 20
#define PPART 8                  // candidate partitions
#define CPB (M_TOTAL / PPART)    // 1024 candidates per K1b block
#define QT 64                    // queries per K1 block
#define SAMPLE 1024              // tau sample = candidates [0, 1024)
#define CAP 64                   // collect capacity per (query,partition); E~20.5, 9-sigma margin
#define SLOTS (PPART * CAP)      // 512 -> 8 slots per lane in K2

typedef __attribute__((ext_vector_type(8))) short bf16x8;  // 8 bf16 (4 VGPRs)
typedef __attribute__((ext_vector_type(4))) float f32x4;

// ---------------------------------------------------------------------------
// K0: per-point precompute.
//   sq[j]   = ||pos_j||^2 (fp32)
//   poshi/poslo: bf16 split of pos (hi = rne-bf16(p), lo = rne-bf16(p - hi))
//   a[j,o]  = b1[o] + f_j @ (W1_top - W1_bot)   (center term of factored L1)
//   g[j,o]  = f_j @ W1_bot                      (neighbor term)
// ---------------------------------------------------------------------------
__global__ __launch_bounds__(256) void k0_pre(
    const float* __restrict__ pos, const float* __restrict__ feat,
    const float* __restrict__ W1, const float* __restrict__ b1,
    float* __restrict__ sq, float* __restrict__ a_out, float* __restrict__ g_out,
    unsigned short* __restrict__ poshi, unsigned short* __restrict__ poslo) {
  __shared__ float fLds[4][64];
  const int lane = threadIdx.x & 63;
  const int rl = threadIdx.x >> 6;
  const int r = blockIdx.x * 4 + rl;

  float p = pos[r * 64 + lane];
  float f = feat[r * 64 + lane];
  fLds[rl][lane] = f;  // wave-private row; wave lockstep

  // bf16 split (RNE)
  unsigned u = __float_as_uint(p);
  unsigned hib = (u + 0x7FFFu + ((u >> 16) & 1u)) >> 16;
  float hif = __uint_as_float(hib << 16);
  float lof = p - hif;
  unsigned v = __float_as_uint(lof);
  unsigned lob = (v + 0x7FFFu + ((v >> 16) & 1u)) >> 16;
  poshi[r * 64 + lane] = (unsigned short)hib;
  poslo[r * 64 + lane] = (unsigned short)lob;

  float s = p * p;
#pragma unroll
  for (int off = 1; off < 64; off <<= 1) s += __shfl_xor(s, off, 64);
  if (lane == 0) sq[r] = s;

  float acc_a = b1[lane];
  float acc_g = 0.f;
  const float4* f4 = reinterpret_cast<const float4*>(fLds[rl]);
#pragma unroll
  for (int i = 0; i < 16; ++i) {
    float4 fv = f4[i];
    float fd[4] = {fv.x, fv.y, fv.z, fv.w};
#pragma unroll
    for (int j = 0; j < 4; ++j) {
      int d = 4 * i + j;
      float wt = W1[d * 64 + lane];
      float wb = W1[(64 + d) * 64 + lane];
      acc_a = fmaf(fd[j], wt - wb, acc_a);
      acc_g = fmaf(fd[j], wb, acc_g);
    }
  }
  a_out[r * 64 + lane] = acc_a;
  g_out[r * 64 + lane] = acc_g;
}

// ---------------------------------------------------------------------------
// MFMA stripe: 64 queries (4 groups of 16) x 16 candidates, K=64, bf16-split
// 3-product (hh + hl + lh) -> ~fp32-accurate dot. 24 MFMAs per call.
// A/B layouts: A[m=lane&15][k=quad*8+j]; B[k=quad*8+j][n=lane&15];
// D: col=lane&15, row=quad*4+reg (m89/m120-verified, AMD matrix calc).
// ---------------------------------------------------------------------------
__device__ __forceinline__ void mfma_stripe(
    const unsigned short* __restrict__ poshi,
    const unsigned short* __restrict__ poslo,
    const bf16x8 (&Ahi)[4][2], const bf16x8 (&Alo)[4][2],
    int candRow, int dimOff, f32x4 (&acc)[4]) {
  const bf16x8 Bhi0 = *(const bf16x8*)(poshi + (size_t)candRow * 64 + dimOff);
  const bf16x8 Bhi1 = *(const bf16x8*)(poshi + (size_t)candRow * 64 + dimOff + 32);
  const bf16x8 Blo0 = *(const bf16x8*)(poslo + (size_t)candRow * 64 + dimOff);
  const bf16x8 Blo1 = *(const bf16x8*)(poslo + (size_t)candRow * 64 + dimOff + 32);
#pragma unroll
  for (int s = 0; s < 4; ++s) {
    f32x4 a = acc[s];
    a = __builtin_amdgcn_mfma_f32_16x16x32_bf16(Ahi[s][0], Bhi0, a, 0, 0, 0);
    a = __builtin_amdgcn_mfma_f32_16x16x32_bf16(Ahi[s][1], Bhi1, a, 0, 0, 0);
    a = __builtin_amdgcn_mfma_f32_16x16x32_bf16(Ahi[s][0], Blo0, a, 0, 0, 0);
    a = __builtin_amdgcn_mfma_f32_16x16x32_bf16(Ahi[s][1], Blo1, a, 0, 0, 0);
    a = __builtin_amdgcn_mfma_f32_16x16x32_bf16(Alo[s][0], Bhi0, a, 0, 0, 0);
    a = __builtin_amdgcn_mfma_f32_16x16x32_bf16(Alo[s][1], Bhi1, a, 0, 0, 0);
    acc[s] = a;
  }
}

// ---------------------------------------------------------------------------
// K1a: per-query threshold tau from a fixed 1024-candidate sample.
// tau_q = EXACT 20th-smallest approx-val over candidates [0,1024), computed
// with the identical MFMA pipeline as K1b (bitwise-consistent d-hat).
// Since sample subset-20th >= full-set 20th (in d-hat space), collecting
// val <= tau in K1b is a guaranteed superset of the approx top-20.
// Structure: MFMA stripes -> LDS transpose -> 4 threads/query keep exact
// top-20 of 256-candidate substreams (register carry-cascade) -> 4-way merge.
// ---------------------------------------------------------------------------
__global__ __launch_bounds__(256) void k1a_tau(
    const unsigned short* __restrict__ poshi,
    const unsigned short* __restrict__ poslo,
    const float* __restrict__ sq, float* __restrict__ tau_g) {
  __shared__ float vLds[64][65];        // 16.25 KiB: [cand-local][query]
  __shared__ float sqcLds[SAMPLE];      // 4 KiB
  __shared__ float topLds[64][4][20];   // 20 KiB: per-query per-quarter sorted
  const int lane = threadIdx.x & 63;
  const int w = threadIdx.x >> 6;
  const int qbase = blockIdx.x * QT;
  const int col = lane & 15;
  const int quad = lane >> 4;
  const int dimOff = quad * 8;
  const int qt = threadIdx.x & 63;      // query owned for selection
  const int quarter = threadIdx.x >> 6; // candidate quarter owned

  for (int i = threadIdx.x; i < SAMPLE; i += 256) sqcLds[i] = sq[i];

  bf16x8 Ahi[4][2], Alo[4][2];
#pragma unroll
  for (int s = 0; s < 4; ++s) {
    int row = qbase + s * 16 + col;
    Ahi[s][0] = *(const bf16x8*)(poshi + (size_t)row * 64 + dimOff);
    Ahi[s][1] = *(const bf16x8*)(poshi + (size_t)row * 64 + dimOff + 32);
    Alo[s][0] = *(const bf16x8*)(poslo + (size_t)row * 64 + dimOff);
    Alo[s][1] = *(const bf16x8*)(poslo + (size_t)row * 64 + dimOff + 32);
  }
  __syncthreads();

  const f32x4 zf = {0.f, 0.f, 0.f, 0.f};
  float bd[KNN];
#pragma unroll
  for (int k = 0; k < KNN; ++k) bd[k] = FLT_MAX;

  for (int c0 = 0; c0 < SAMPLE; c0 += 64) {
    const int candRow = c0 + w * 16 + col;  // sample base 0
    f32x4 acc[4] = {zf, zf, zf, zf};
    mfma_stripe(poshi, poslo, Ahi, Alo, candRow, dimOff, acc);
    const float sqcv = sqcLds[c0 + w * 16 + col] + 256.0f;
#pragma unroll
    for (int s = 0; s < 4; ++s) {
#pragma unroll
      for (int r = 0; r < 4; ++r) {
        float val = fmaf(-2.f, acc[s][r], sqcv);
        vLds[w * 16 + col][s * 16 + quad * 4 + r] = val;
      }
    }
    __syncthreads();
    // each thread consumes its 16 (query qt, candidates quarter*16..+15)
#pragma unroll
    for (int i = 0; i < 16; ++i) {
      float v = vLds[quarter * 16 + i][qt];
      if (v < bd[KNN - 1]) {
        float cd = v;
#pragma unroll
        for (int k = 0; k < KNN; ++k) {
          bool sw = cd < bd[k];
          float nd = sw ? bd[k] : cd;
          bd[k] = sw ? cd : bd[k];
          cd = nd;
        }
      }
    }
    __syncthreads();
  }

#pragma unroll
  for (int k = 0; k < KNN; ++k) topLds[qt][quarter][k] = bd[k];
  __syncthreads();

  if (threadIdx.x < QT) {
    const int q = threadIdx.x;
    int p0 = 0, p1 = 0, p2 = 0, p3 = 0;
    float tau = FLT_MAX;
    for (int k = 0; k < KNN; ++k) {
      float v0 = (p0 < KNN) ? topLds[q][0][p0] : FLT_MAX;
      float v1 = (p1 < KNN) ? topLds[q][1][p1] : FLT_MAX;
      float v2 = (p2 < KNN) ? topLds[q][2][p2] : FLT_MAX;
      float v3 = (p3 < KNN) ? topLds[q][3][p3] : FLT_MAX;
      float m01 = fminf(v0, v1), m23 = fminf(v2, v3);
      float m = fminf(m01, m23);
      if (m == v0) p0++;
      else if (m == v1) p1++;
      else if (m == v2) p2++;
      else p3++;
      tau = m;
    }
    tau_g[qbase + q] = tau;  // exact sample 20th-smallest (d-hat space)
  }
}

// ---------------------------------------------------------------------------
// K1b: single MFMA pass over a 1024-candidate partition; collect every
// candidate with val <= tau_q into the per-(query,partition) list.
// Grid (128 qtiles, 8 partitions).
// ---------------------------------------------------------------------------
__global__ __launch_bounds__(256) void k1b_collect(
    const unsigned short* __restrict__ poshi,
    const unsigned short* __restrict__ poslo,
    const float* __restrict__ sq, const float* __restrict__ tau_g,
    unsigned* __restrict__ list, unsigned* __restrict__ cnt_ws) {
  __shared__ float sqcLds[CPB];   // 4 KiB
  __shared__ float tauLds[QT];
  __shared__ unsigned cntLds[QT];

  const int lane = threadIdx.x & 63;
  const int w = threadIdx.x >> 6;
  const int qbase = blockIdx.x * QT;
  const int cbase = blockIdx.y * CPB;
  const int col = lane & 15;
  const int quad = lane >> 4;
  const int dimOff = quad * 8;

  for (int i = threadIdx.x; i < CPB; i += 256) sqcLds[i] = sq[cbase + i];
  if (threadIdx.x < QT) {
    tauLds[threadIdx.x] = tau_g[qbase + threadIdx.x];
    cntLds[threadIdx.x] = 0;
  }

  bf16x8 Ahi[4][2], Alo[4][2];
#pragma unroll
  for (int s = 0; s < 4; ++s) {
    int row = qbase + s * 16 + col;
    Ahi[s][0] = *(const bf16x8*)(poshi + (size_t)row * 64 + dimOff);
    Ahi[s][1] = *(const bf16x8*)(poshi + (size_t)row * 64 + dimOff + 32);
    Alo[s][0] = *(const bf16x8*)(poslo + (size_t)row * 64 + dimOff);
    Alo[s][1] = *(const bf16x8*)(poslo + (size_t)row * 64 + dimOff + 32);
  }
  __syncthreads();

  float tau_l[4][4];
#pragma unroll
  for (int s = 0; s < 4; ++s)
#pragma unroll
    for (int r = 0; r < 4; ++r) tau_l[s][r] = tauLds[s * 16 + quad * 4 + r];

  const f32x4 zf = {0.f, 0.f, 0.f, 0.f};
  for (int c0 = 0; c0 < CPB; c0 += 64) {
    const int candRow = cbase + c0 + w * 16 + col;
    f32x4 acc[4] = {zf, zf, zf, zf};
    mfma_stripe(poshi, poslo, Ahi, Alo, candRow, dimOff, acc);
    const float sqcv = sqcLds[c0 + w * 16 + col] + 256.0f;
#pragma unroll
    for (int s = 0; s < 4; ++s) {
#pragma unroll
      for (int r = 0; r < 4; ++r) {
        float val = fmaf(-2.f, acc[s][r], sqcv);
        const int qrow = s * 16 + quad * 4 + r;  // D row = quad*4+reg
        if (val <= tau_l[s][r]) {  // ~2% of lanes
          unsigned slot = atomicAdd(&cntLds[qrow], 1u);
          if (slot < CAP)
            list[(size_t)(qbase + qrow) * SLOTS + blockIdx.y * CAP + slot] =
                (unsigned)candRow;
        }
      }
    }
  }
  __syncthreads();
  if (threadIdx.x < QT) {
    unsigned c = cntLds[threadIdx.x];
    cnt_ws[(qbase + threadIdx.x) * PPART + blockIdx.y] = c > CAP ? CAP : c;
  }
}

// ---------------------------------------------------------------------------
// K2: exact re-rank of collected candidates + factored MLP + max-agg.
// One wave per query; 8 slots/lane; exact fp32 d2; sort-8; 20x wave-min
// extraction on u64 (d2bits<<32|idx) keys; per-k LDS transpose + GEMV.
// ---------------------------------------------------------------------------
__global__ __launch_bounds__(256) void k2_mlp(
    const float* __restrict__ pos, const float* __restrict__ sq,
    const float* __restrict__ a_in, const float* __restrict__ g_in,
    const float* __restrict__ W2, const float* __restrict__ b2,
    const unsigned* __restrict__ list, const unsigned* __restrict__ cnt_ws,
    float* __restrict__ out) {
  __shared__ float qpLds[4][64];
  __shared__ float hLds[4][64];
  const int lane = threadIdx.x & 63;
  const int wv = threadIdx.x >> 6;
  const int q = blockIdx.x * 4 + wv;

  qpLds[wv][lane] = pos[(size_t)q * 64 + lane];
  __builtin_amdgcn_wave_barrier();

  const float sqq = sq[q];

  unsigned cnt_l[PPART];
#pragma unroll
  for (int p = 0; p < PPART; ++p) cnt_l[p] = cnt_ws[q * PPART + p];

  unsigned long long key[8];
#pragma unroll
  for (int i = 0; i < 8; ++i) {
    const int flat = i * 64 + lane;
    const int p = flat >> 6;   // CAP = 64
    const int sl = flat & 63;
    const bool valid = (unsigned)sl < cnt_l[p];
    unsigned long long kk = ~0ull;
    if (valid) {
      const unsigned idx = list[(size_t)q * SLOTS + flat];
      const float4* cp4 = reinterpret_cast<const float4*>(pos + (size_t)idx * 64);
      const float4* qp4 = reinterpret_cast<const float4*>(qpLds[wv]);
      float d0 = 0.f, d1 = 0.f, d2 = 0.f, d3 = 0.f;
#pragma unroll
      for (int t = 0; t < 16; ++t) {
        float4 cv = cp4[t];
        float4 qv = qp4[t];
        d0 = fmaf(cv.x, qv.x, d0);
        d1 = fmaf(cv.y, qv.y, d1);
        d2 = fmaf(cv.z, qv.z, d2);
        d3 = fmaf(cv.w, qv.w, d3);
      }
      float dot = (d0 + d1) + (d2 + d3);
      float dd = fmaxf(fmaf(-2.f, dot, sqq + sq[idx]), 0.f);
      kk = ((unsigned long long)__float_as_uint(dd) << 32) | idx;
    }
    key[i] = kk;
  }
  // sort 8 keys ascending (Knuth 19-comparator network)
#define CSWAP(x, y)                                            \
  {                                                            \
    unsigned long long lo = key[x] < key[y] ? key[x] : key[y]; \
    unsigned long long hi = key[x] < key[y] ? key[y] : key[x]; \
    key[x] = lo; key[y] = hi;                                  \
  }
  CSWAP(0, 1) CSWAP(2, 3) CSWAP(4, 5) CSWAP(6, 7)
  CSWAP(0, 2) CSWAP(1, 3) CSWAP(4, 6) CSWAP(5, 7)
  CSWAP(1, 2) CSWAP(5, 6) CSWAP(0, 4) CSWAP(3, 7)
  CSWAP(1, 5) CSWAP(2, 6)
  CSWAP(1, 4) CSWAP(3, 6)
  CSWAP(2, 4) CSWAP(3, 5)
  CSWAP(3, 4)
#undef CSWAP

  float w2[64];
#pragma unroll
  for (int d = 0; d < 64; ++d) w2[d] = W2[d * 64 + lane];
  const float aq = a_in[(size_t)q * 64 + lane];

  float omax = -FLT_MAX;
#pragma unroll
  for (int k = 0; k < KNN; ++k) {
    unsigned long long m = key[0];
#pragma unroll
    for (int s = 1; s < 64; s <<= 1) {
      unsigned long long o = __shfl_xor(m, s, 64);
      m = o < m ? o : m;
    }
    const bool win = (key[0] == m);  // unique (idx embedded)
#pragma unroll
    for (int i = 0; i < 7; ++i) key[i] = win ? key[i + 1] : key[i];
    key[7] = win ? ~0ull : key[7];
    const unsigned n = (unsigned)(m & 0xFFFFFFFFu);  // wave-uniform

    float hv = fmaxf(aq + g_in[(size_t)n * 64 + lane], 0.f);
    hLds[wv][lane] = hv;
    __builtin_amdgcn_wave_barrier();
    float s0 = 0.f, s1 = 0.f, s2 = 0.f, s3 = 0.f;
    const float4* h4 = reinterpret_cast<const float4*>(hLds[wv]);
#pragma unroll
    for (int i = 0; i < 16; ++i) {
      float4 hv4 = h4[i];
      s0 = fmaf(hv4.x, w2[4 * i + 0], s0);
      s1 = fmaf(hv4.y, w2[4 * i + 1], s1);
      s2 = fmaf(hv4.z, w2[4 * i + 2], s2);
      s3 = fmaf(hv4.w, w2[4 * i + 3], s3);
    }
    omax = fmaxf(omax, (s0 + s1) + (s2 + s3));
    __builtin_amdgcn_wave_barrier();
  }
  out[(size_t)q * 64 + lane] = omax + b2[lane];
}

// ---------------------------------------------------------------------------
extern "C" void kernel_launch(void* const* d_in, const int* in_sizes, int n_in,
                              void* d_out, int out_size, void* d_ws, size_t ws_size,
                              hipStream_t stream) {
  const float* pos = (const float*)d_in[0];
  const float* feat = (const float*)d_in[1];
  const float* W1 = (const float*)d_in[2];
  const float* b1 = (const float*)d_in[3];
  const float* W2 = (const float*)d_in[4];
  const float* b2 = (const float*)d_in[5];
  float* out = (float*)d_out;

  // ws layout (bytes):
  //   sq      @ 0         32 KiB
  //   a       @ 32768     2 MiB
  //   g       @ 2129920   2 MiB
  //   poshi   @ 4227072   1 MiB
  //   poslo   @ 5275648   1 MiB
  //   list    @ 6324224   16 MiB   (8192 * 512 * 4)
  //   cnt     @ 23101440  256 KiB
  //   tau     @ 23363584  32 KiB      total ~22.3 MiB
  char* ws = (char*)d_ws;
  float* sq = (float*)ws;
  float* a = (float*)(ws + 32768);
  float* g = (float*)(ws + 2129920);
  unsigned short* poshi = (unsigned short*)(ws + 4227072);
  unsigned short* poslo = (unsigned short*)(ws + 5275648);
  unsigned* list = (unsigned*)(ws + 6324224);
  unsigned* cnt_ws = (unsigned*)(ws + 23101440);
  float* tau_g = (float*)(ws + 23363584);

  k0_pre<<<M_TOTAL / 4, 256, 0, stream>>>(pos, feat, W1, b1, sq, a, g, poshi, poslo);
  k1a_tau<<<M_TOTAL / QT, 256, 0, stream>>>(poshi, poslo, sq, tau_g);
  k1b_collect<<<dim3(M_TOTAL / QT, PPART), 256, 0, stream>>>(poshi, poslo, sq, tau_g, list, cnt_ws);
  k2_mlp<<<M_TOTAL / 4, 256, 0, stream>>>(pos, sq, a, g, W2, b2, list, cnt_ws, out);
}

// Round 5
// 355.351 us; speedup vs baseline: 1.8661x; 1.0530x over previous
//
#include <hip/hip_runtime.h>
#include <cfloat>
#include <cstdint>

// Problem constants (B=4, N=2048, C=64, O=64, K=20)
#define M_TOTAL 8192
#define KNN 20
#define PPART 8                  // candidate partitions
#define CPB (M_TOTAL / PPART)    // 1024 candidates per K1b block
#define QT 64                    // queries per K1 block
#define SAMPLE 1024              // tau sample = candidates [0, 1024)
#define CAP 64                   // collect capacity per (query,partition); E~20.5, 9-sigma margin
#define SLOTS (PPART * CAP)      // 512 -> 8 slots per lane in K2

typedef __attribute__((ext_vector_type(8))) short bf16x8;  // 8 bf16 (4 VGPRs)
typedef __attribute__((ext_vector_type(4))) float f32x4;

// ---------------------------------------------------------------------------
// K0: per-point precompute.
//   sq[j]   = ||pos_j||^2 (fp32)
//   poshi/poslo: bf16 split of pos (hi = rne-bf16(p), lo = rne-bf16(p - hi))
//   a[j,o]  = b1[o] + f_j @ (W1_top - W1_bot)   (center term of factored L1)
//   g[j,o]  = f_j @ W1_bot                      (neighbor term)
// ---------------------------------------------------------------------------
__global__ __launch_bounds__(256) void k0_pre(
    const float* __restrict__ pos, const float* __restrict__ feat,
    const float* __restrict__ W1, const float* __restrict__ b1,
    float* __restrict__ sq, float* __restrict__ a_out, float* __restrict__ g_out,
    unsigned short* __restrict__ poshi, unsigned short* __restrict__ poslo) {
  __shared__ float fLds[4][64];
  const int lane = threadIdx.x & 63;
  const int rl = threadIdx.x >> 6;
  const int r = blockIdx.x * 4 + rl;

  float p = pos[r * 64 + lane];
  float f = feat[r * 64 + lane];
  fLds[rl][lane] = f;  // wave-private row; wave lockstep

  // bf16 split (RNE)
  unsigned u = __float_as_uint(p);
  unsigned hib = (u + 0x7FFFu + ((u >> 16) & 1u)) >> 16;
  float hif = __uint_as_float(hib << 16);
  float lof = p - hif;
  unsigned v = __float_as_uint(lof);
  unsigned lob = (v + 0x7FFFu + ((v >> 16) & 1u)) >> 16;
  poshi[r * 64 + lane] = (unsigned short)hib;
  poslo[r * 64 + lane] = (unsigned short)lob;

  float s = p * p;
#pragma unroll
  for (int off = 1; off < 64; off <<= 1) s += __shfl_xor(s, off, 64);
  if (lane == 0) sq[r] = s;

  float acc_a = b1[lane];
  float acc_g = 0.f;
  const float4* f4 = reinterpret_cast<const float4*>(fLds[rl]);
#pragma unroll
  for (int i = 0; i < 16; ++i) {
    float4 fv = f4[i];
    float fd[4] = {fv.x, fv.y, fv.z, fv.w};
#pragma unroll
    for (int j = 0; j < 4; ++j) {
      int d = 4 * i + j;
      float wt = W1[d * 64 + lane];
      float wb = W1[(64 + d) * 64 + lane];
      acc_a = fmaf(fd[j], wt - wb, acc_a);
      acc_g = fmaf(fd[j], wb, acc_g);
    }
  }
  a_out[r * 64 + lane] = acc_a;
  g_out[r * 64 + lane] = acc_g;
}

// ---------------------------------------------------------------------------
// MFMA stripe: 64 queries (4 groups of 16) x 16 candidates, K=64, bf16-split
// 3-product (hh + hl + lh) -> ~fp32-accurate dot. 24 MFMAs per call.
// A/B layouts: A[m=lane&15][k=quad*8+j]; B[k=quad*8+j][n=lane&15];
// D: col=lane&15, row=quad*4+reg (m89/m120-verified).
// ---------------------------------------------------------------------------
__device__ __forceinline__ void mfma_stripe(
    const unsigned short* __restrict__ poshi,
    const unsigned short* __restrict__ poslo,
    const bf16x8 (&Ahi)[4][2], const bf16x8 (&Alo)[4][2],
    int candRow, int dimOff, f32x4 (&acc)[4]) {
  const bf16x8 Bhi0 = *(const bf16x8*)(poshi + (size_t)candRow * 64 + dimOff);
  const bf16x8 Bhi1 = *(const bf16x8*)(poshi + (size_t)candRow * 64 + dimOff + 32);
  const bf16x8 Blo0 = *(const bf16x8*)(poslo + (size_t)candRow * 64 + dimOff);
  const bf16x8 Blo1 = *(const bf16x8*)(poslo + (size_t)candRow * 64 + dimOff + 32);
#pragma unroll
  for (int s = 0; s < 4; ++s) {
    f32x4 a = acc[s];
    a = __builtin_amdgcn_mfma_f32_16x16x32_bf16(Ahi[s][0], Bhi0, a, 0, 0, 0);
    a = __builtin_amdgcn_mfma_f32_16x16x32_bf16(Ahi[s][1], Bhi1, a, 0, 0, 0);
    a = __builtin_amdgcn_mfma_f32_16x16x32_bf16(Ahi[s][0], Blo0, a, 0, 0, 0);
    a = __builtin_amdgcn_mfma_f32_16x16x32_bf16(Ahi[s][1], Blo1, a, 0, 0, 0);
    a = __builtin_amdgcn_mfma_f32_16x16x32_bf16(Alo[s][0], Bhi0, a, 0, 0, 0);
    a = __builtin_amdgcn_mfma_f32_16x16x32_bf16(Alo[s][1], Bhi1, a, 0, 0, 0);
    acc[s] = a;
  }
}

// ---------------------------------------------------------------------------
// K1a: per-query threshold tau = EXACT 20th-smallest approx-val over the
// fixed 1024-candidate sample (same MFMA pipeline as K1b -> bitwise-
// consistent d-hat; sample-20th >= full-20th => K1b collect is a superset).
//
// v2 (this round): NO block barriers in the stripe loop. Wave w computes the
// full 64-query x 16-cand tile for cols 16w..16w+16 each stripe, transposes
// through a wave-PRIVATE LDS region (wave_barrier only, same pattern as K2's
// hLds round-trip), and lane l maintains query l's top-20 over wave w's 256
// candidates in registers. One __syncthreads before the final 4-way merge.
// ---------------------------------------------------------------------------
__global__ __launch_bounds__(256) void k1a_tau(
    const unsigned short* __restrict__ poshi,
    const unsigned short* __restrict__ poslo,
    const float* __restrict__ sq, float* __restrict__ tau_g) {
  __shared__ float vw[4][16][68];       // wave-private transpose, 17.4 KiB
  __shared__ float sqcLds[SAMPLE];      // 4 KiB
  __shared__ float topLds[64][4][20];   // 20 KiB
  const int lane = threadIdx.x & 63;
  const int w = threadIdx.x >> 6;
  const int qbase = blockIdx.x * QT;
  const int col = lane & 15;
  const int quad = lane >> 4;
  const int dimOff = quad * 8;

  for (int i = threadIdx.x; i < SAMPLE; i += 256) sqcLds[i] = sq[i];

  bf16x8 Ahi[4][2], Alo[4][2];
#pragma unroll
  for (int s = 0; s < 4; ++s) {
    int row = qbase + s * 16 + col;
    Ahi[s][0] = *(const bf16x8*)(poshi + (size_t)row * 64 + dimOff);
    Ahi[s][1] = *(const bf16x8*)(poshi + (size_t)row * 64 + dimOff + 32);
    Alo[s][0] = *(const bf16x8*)(poslo + (size_t)row * 64 + dimOff);
    Alo[s][1] = *(const bf16x8*)(poslo + (size_t)row * 64 + dimOff + 32);
  }
  __syncthreads();  // sqcLds ready

  const f32x4 zf = {0.f, 0.f, 0.f, 0.f};
  float bd[KNN];
#pragma unroll
  for (int k = 0; k < KNN; ++k) bd[k] = FLT_MAX;

  for (int c0 = 0; c0 < SAMPLE; c0 += 64) {
    const int candRow = c0 + w * 16 + col;
    f32x4 acc[4] = {zf, zf, zf, zf};
    mfma_stripe(poshi, poslo, Ahi, Alo, candRow, dimOff, acc);
    const float sqcv = sqcLds[candRow] + 256.0f;
    // write this wave's 64q x 16c tile: queries quad*4+r are consecutive -> b128
#pragma unroll
    for (int s = 0; s < 4; ++s) {
      float4 v4;
      v4.x = fmaf(-2.f, acc[s][0], sqcv);
      v4.y = fmaf(-2.f, acc[s][1], sqcv);
      v4.z = fmaf(-2.f, acc[s][2], sqcv);
      v4.w = fmaf(-2.f, acc[s][3], sqcv);
      *reinterpret_cast<float4*>(&vw[w][col][s * 16 + quad * 4]) = v4;
    }
    __builtin_amdgcn_wave_barrier();  // wave-lockstep; region is wave-private
    // lane l = query l: consume 16 candidate values (stride-68 -> 2 lanes/bank)
#pragma unroll
    for (int i = 0; i < 16; ++i) {
      float v = vw[w][i][lane];
      if (v < bd[KNN - 1]) {
        float cd = v;
#pragma unroll
        for (int k = 0; k < KNN; ++k) {
          bool sw = cd < bd[k];
          float nd = sw ? bd[k] : cd;
          bd[k] = sw ? cd : bd[k];
          cd = nd;
        }
      }
    }
    __builtin_amdgcn_wave_barrier();
  }

#pragma unroll
  for (int k = 0; k < KNN; ++k) topLds[lane][w][k] = bd[k];
  __syncthreads();

  if (threadIdx.x < QT) {
    const int q = threadIdx.x;
    int p0 = 0, p1 = 0, p2 = 0, p3 = 0;
    float tau = FLT_MAX;
    for (int k = 0; k < KNN; ++k) {
      float v0 = (p0 < KNN) ? topLds[q][0][p0] : FLT_MAX;
      float v1 = (p1 < KNN) ? topLds[q][1][p1] : FLT_MAX;
      float v2 = (p2 < KNN) ? topLds[q][2][p2] : FLT_MAX;
      float v3 = (p3 < KNN) ? topLds[q][3][p3] : FLT_MAX;
      float m01 = fminf(v0, v1), m23 = fminf(v2, v3);
      float m = fminf(m01, m23);
      if (m == v0) p0++;
      else if (m == v1) p1++;
      else if (m == v2) p2++;
      else p3++;
      tau = m;
    }
    tau_g[qbase + q] = tau;  // exact sample 20th-smallest (d-hat space)
  }
}

// ---------------------------------------------------------------------------
// K1b: single MFMA pass over a 1024-candidate partition; collect every
// candidate with val <= tau_q into the per-(query,partition) list.
// Grid (128 qtiles, 8 partitions).
// ---------------------------------------------------------------------------
__global__ __launch_bounds__(256) void k1b_collect(
    const unsigned short* __restrict__ poshi,
    const unsigned short* __restrict__ poslo,
    const float* __restrict__ sq, const float* __restrict__ tau_g,
    unsigned* __restrict__ list, unsigned* __restrict__ cnt_ws) {
  __shared__ float sqcLds[CPB];   // 4 KiB
  __shared__ float tauLds[QT];
  __shared__ unsigned cntLds[QT];

  const int lane = threadIdx.x & 63;
  const int w = threadIdx.x >> 6;
  const int qbase = blockIdx.x * QT;
  const int cbase = blockIdx.y * CPB;
  const int col = lane & 15;
  const int quad = lane >> 4;
  const int dimOff = quad * 8;

  for (int i = threadIdx.x; i < CPB; i += 256) sqcLds[i] = sq[cbase + i];
  if (threadIdx.x < QT) {
    tauLds[threadIdx.x] = tau_g[qbase + threadIdx.x];
    cntLds[threadIdx.x] = 0;
  }

  bf16x8 Ahi[4][2], Alo[4][2];
#pragma unroll
  for (int s = 0; s < 4; ++s) {
    int row = qbase + s * 16 + col;
    Ahi[s][0] = *(const bf16x8*)(poshi + (size_t)row * 64 + dimOff);
    Ahi[s][1] = *(const bf16x8*)(poshi + (size_t)row * 64 + dimOff + 32);
    Alo[s][0] = *(const bf16x8*)(poslo + (size_t)row * 64 + dimOff);
    Alo[s][1] = *(const bf16x8*)(poslo + (size_t)row * 64 + dimOff + 32);
  }
  __syncthreads();

  float tau_l[4][4];
#pragma unroll
  for (int s = 0; s < 4; ++s)
#pragma unroll
    for (int r = 0; r < 4; ++r) tau_l[s][r] = tauLds[s * 16 + quad * 4 + r];

  const f32x4 zf = {0.f, 0.f, 0.f, 0.f};
  for (int c0 = 0; c0 < CPB; c0 += 64) {
    const int candRow = cbase + c0 + w * 16 + col;
    f32x4 acc[4] = {zf, zf, zf, zf};
    mfma_stripe(poshi, poslo, Ahi, Alo, candRow, dimOff, acc);
    const float sqcv = sqcLds[c0 + w * 16 + col] + 256.0f;
#pragma unroll
    for (int s = 0; s < 4; ++s) {
#pragma unroll
      for (int r = 0; r < 4; ++r) {
        float val = fmaf(-2.f, acc[s][r], sqcv);
        const int qrow = s * 16 + quad * 4 + r;  // D row = quad*4+reg
        if (val <= tau_l[s][r]) {  // ~2% of lanes
          unsigned slot = atomicAdd(&cntLds[qrow], 1u);
          if (slot < CAP)
            list[(size_t)(qbase + qrow) * SLOTS + blockIdx.y * CAP + slot] =
                (unsigned)candRow;
        }
      }
    }
  }
  __syncthreads();
  if (threadIdx.x < QT) {
    unsigned c = cntLds[threadIdx.x];
    cnt_ws[(qbase + threadIdx.x) * PPART + blockIdx.y] = c > CAP ? CAP : c;
  }
}

// ---------------------------------------------------------------------------
// K2: exact re-rank of collected candidates + factored MLP + max-agg.
// One wave per query; 8 slots/lane; exact fp32 d2; sort-8; 20x wave-min
// extraction on u64 (d2bits<<32|idx) keys; per-k LDS transpose + GEMV.
// ---------------------------------------------------------------------------
__global__ __launch_bounds__(256) void k2_mlp(
    const float* __restrict__ pos, const float* __restrict__ sq,
    const float* __restrict__ a_in, const float* __restrict__ g_in,
    const float* __restrict__ W2, const float* __restrict__ b2,
    const unsigned* __restrict__ list, const unsigned* __restrict__ cnt_ws,
    float* __restrict__ out) {
  __shared__ float qpLds[4][64];
  __shared__ float hLds[4][64];
  const int lane = threadIdx.x & 63;
  const int wv = threadIdx.x >> 6;
  const int q = blockIdx.x * 4 + wv;

  qpLds[wv][lane] = pos[(size_t)q * 64 + lane];
  __builtin_amdgcn_wave_barrier();

  const float sqq = sq[q];

  unsigned cnt_l[PPART];
#pragma unroll
  for (int p = 0; p < PPART; ++p) cnt_l[p] = cnt_ws[q * PPART + p];

  unsigned long long key[8];
#pragma unroll
  for (int i = 0; i < 8; ++i) {
    const int flat = i * 64 + lane;
    const int p = flat >> 6;   // CAP = 64
    const int sl = flat & 63;
    const bool valid = (unsigned)sl < cnt_l[p];
    unsigned long long kk = ~0ull;
    if (valid) {
      const unsigned idx = list[(size_t)q * SLOTS + flat];
      const float4* cp4 = reinterpret_cast<const float4*>(pos + (size_t)idx * 64);
      const float4* qp4 = reinterpret_cast<const float4*>(qpLds[wv]);
      float d0 = 0.f, d1 = 0.f, d2 = 0.f, d3 = 0.f;
#pragma unroll
      for (int t = 0; t < 16; ++t) {
        float4 cv = cp4[t];
        float4 qv = qp4[t];
        d0 = fmaf(cv.x, qv.x, d0);
        d1 = fmaf(cv.y, qv.y, d1);
        d2 = fmaf(cv.z, qv.z, d2);
        d3 = fmaf(cv.w, qv.w, d3);
      }
      float dot = (d0 + d1) + (d2 + d3);
      float dd = fmaxf(fmaf(-2.f, dot, sqq + sq[idx]), 0.f);
      kk = ((unsigned long long)__float_as_uint(dd) << 32) | idx;
    }
    key[i] = kk;
  }
  // sort 8 keys ascending (Knuth 19-comparator network)
#define CSWAP(x, y)                                            \
  {                                                            \
    unsigned long long lo = key[x] < key[y] ? key[x] : key[y]; \
    unsigned long long hi = key[x] < key[y] ? key[y] : key[x]; \
    key[x] = lo; key[y] = hi;                                  \
  }
  CSWAP(0, 1) CSWAP(2, 3) CSWAP(4, 5) CSWAP(6, 7)
  CSWAP(0, 2) CSWAP(1, 3) CSWAP(4, 6) CSWAP(5, 7)
  CSWAP(1, 2) CSWAP(5, 6) CSWAP(0, 4) CSWAP(3, 7)
  CSWAP(1, 5) CSWAP(2, 6)
  CSWAP(1, 4) CSWAP(3, 6)
  CSWAP(2, 4) CSWAP(3, 5)
  CSWAP(3, 4)
#undef CSWAP

  float w2[64];
#pragma unroll
  for (int d = 0; d < 64; ++d) w2[d] = W2[d * 64 + lane];
  const float aq = a_in[(size_t)q * 64 + lane];

  float omax = -FLT_MAX;
#pragma unroll
  for (int k = 0; k < KNN; ++k) {
    unsigned long long m = key[0];
#pragma unroll
    for (int s = 1; s < 64; s <<= 1) {
      unsigned long long o = __shfl_xor(m, s, 64);
      m = o < m ? o : m;
    }
    const bool win = (key[0] == m);  // unique (idx embedded)
#pragma unroll
    for (int i = 0; i < 7; ++i) key[i] = win ? key[i + 1] : key[i];
    key[7] = win ? ~0ull : key[7];
    const unsigned n = (unsigned)(m & 0xFFFFFFFFu);  // wave-uniform

    float hv = fmaxf(aq + g_in[(size_t)n * 64 + lane], 0.f);
    hLds[wv][lane] = hv;
    __builtin_amdgcn_wave_barrier();
    float s0 = 0.f, s1 = 0.f, s2 = 0.f, s3 = 0.f;
    const float4* h4 = reinterpret_cast<const float4*>(hLds[wv]);
#pragma unroll
    for (int i = 0; i < 16; ++i) {
      float4 hv4 = h4[i];
      s0 = fmaf(hv4.x, w2[4 * i + 0], s0);
      s1 = fmaf(hv4.y, w2[4 * i + 1], s1);
      s2 = fmaf(hv4.z, w2[4 * i + 2], s2);
      s3 = fmaf(hv4.w, w2[4 * i + 3], s3);
    }
    omax = fmaxf(omax, (s0 + s1) + (s2 + s3));
    __builtin_amdgcn_wave_barrier();
  }
  out[(size_t)q * 64 + lane] = omax + b2[lane];
}

// ---------------------------------------------------------------------------
extern "C" void kernel_launch(void* const* d_in, const int* in_sizes, int n_in,
                              void* d_out, int out_size, void* d_ws, size_t ws_size,
                              hipStream_t stream) {
  const float* pos = (const float*)d_in[0];
  const float* feat = (const float*)d_in[1];
  const float* W1 = (const float*)d_in[2];
  const float* b1 = (const float*)d_in[3];
  const float* W2 = (const float*)d_in[4];
  const float* b2 = (const float*)d_in[5];
  float* out = (float*)d_out;

  // ws layout (bytes):
  //   sq      @ 0         32 KiB
  //   a       @ 32768     2 MiB
  //   g       @ 2129920   2 MiB
  //   poshi   @ 4227072   1 MiB
  //   poslo   @ 5275648   1 MiB
  //   list    @ 6324224   16 MiB   (8192 * 512 * 4)
  //   cnt     @ 23101440  256 KiB
  //   tau     @ 23363584  32 KiB      total ~22.3 MiB
  char* ws = (char*)d_ws;
  float* sq = (float*)ws;
  float* a = (float*)(ws + 32768);
  float* g = (float*)(ws + 2129920);
  unsigned short* poshi = (unsigned short*)(ws + 4227072);
  unsigned short* poslo = (unsigned short*)(ws + 5275648);
  unsigned* list = (unsigned*)(ws + 6324224);
  unsigned* cnt_ws = (unsigned*)(ws + 23101440);
  float* tau_g = (float*)(ws + 23363584);

  k0_pre<<<M_TOTAL / 4, 256, 0, stream>>>(pos, feat, W1, b1, sq, a, g, poshi, poslo);
  k1a_tau<<<M_TOTAL / QT, 256, 0, stream>>>(poshi, poslo, sq, tau_g);
  k1b_collect<<<dim3(M_TOTAL / QT, PPART), 256, 0, stream>>>(poshi, poslo, sq, tau_g, list, cnt_ws);
  k2_mlp<<<M_TOTAL / 4, 256, 0, stream>>>(pos, sq, a, g, W2, b2, list, cnt_ws, out);
}